// Round 2
// baseline (1260.821 us; speedup 1.0000x reference)
//
#include <hip/hip_runtime.h>
#include <hip/hip_bf16.h>
#include <stdint.h>

// Attention_47528108097749: llama attention block. Inputs/outputs are FLOAT32
// (per reference dtypes). Internal compute in bf16 MFMA (no fp32 MFMA on CDNA4).
// B=2, T=2048, D=4096, H=32, KV=8, HD=128. start_pos=0, mask unused.

typedef short bf16x8 __attribute__((ext_vector_type(8)));
typedef float f32x4  __attribute__((ext_vector_type(4)));

#define GLB_AS(p) ((__attribute__((address_space(1))) void*)(p))
#define LDS_AS(p) ((__attribute__((address_space(3))) void*)(p))

__device__ __forceinline__ float bf2f(ushort u) {
    union { unsigned int i; float f; } v; v.i = ((unsigned int)u) << 16; return v.f;
}
__device__ __forceinline__ ushort f2bf(float f) {
    union { float f; unsigned int i; } v; v.f = f;
    unsigned int r = v.i + 0x7FFFu + ((v.i >> 16) & 1u);   // round-nearest-even
    return (ushort)(r >> 16);
}
__device__ __forceinline__ void store_c(ushort* p, float v) { *p = f2bf(v); }
__device__ __forceinline__ void store_c(float*  p, float v) { *p = v; }

// ---------------------------------------------------------------------------
// f32 -> bf16 cast, vectorized 4-wide. n multiple of 4.
// ---------------------------------------------------------------------------
__global__ __launch_bounds__(256) void cast_f2b(
    const float4* __restrict__ src, ushort4* __restrict__ dst, int n4)
{
    int i = blockIdx.x * 256 + threadIdx.x;
    if (i < n4) {
        float4 v = src[i];
        ushort4 o;
        o.x = f2bf(v.x); o.y = f2bf(v.y); o.z = f2bf(v.z); o.w = f2bf(v.w);
        dst[i] = o;
    }
}

// ---------------------------------------------------------------------------
// NT GEMM: C[m][n] = sum_k A[m][k]*B[n][k]; A,B row-major bf16. C f32 or bf16.
// m97 structure: 128x128 tile, BK=32, 4 waves (2x2 of 64x64), 16x16x32 bf16
// MFMA, global_load_lds width=16 staging. M,N mult of 128; K mult of 32.
// ---------------------------------------------------------------------------
template <typename OT>
__global__ __launch_bounds__(256) void gemm_nt(
    const ushort* __restrict__ A, const ushort* __restrict__ B,
    OT* __restrict__ C, int M, int N, int K)
{
    __shared__ __align__(16) ushort lA[128 * 32];
    __shared__ __align__(16) ushort lB[128 * 32];

    const int tid  = threadIdx.x;
    const int lane = tid & 63;
    const int w    = tid >> 6;
    const int wm   = w >> 1, wn = w & 1;
    const int quad = lane >> 4, l16 = lane & 15;
    const int bm   = blockIdx.y * 128, bn = blockIdx.x * 128;

    f32x4 acc[4][4];
#pragma unroll
    for (int i = 0; i < 4; i++)
#pragma unroll
        for (int j = 0; j < 4; j++) acc[i][j] = (f32x4){0.f, 0.f, 0.f, 0.f};

    const ushort* pa0 = A + (size_t)(bm + (tid >> 2)) * K + (tid & 3) * 8;
    const ushort* pb0 = B + (size_t)(bn + (tid >> 2)) * K + (tid & 3) * 8;
    char* ldsA0 = (char*)lA + (tid & 192) * 16;
    char* ldsA1 = ldsA0 + 4096;
    char* ldsB0 = (char*)lB + (tid & 192) * 16;
    char* ldsB1 = ldsB0 + 4096;
    const size_t rowskip = (size_t)64 * K;

    for (int k0 = 0; k0 < K; k0 += 32) {
        __builtin_amdgcn_global_load_lds(GLB_AS(pa0 + k0),           LDS_AS(ldsA0), 16, 0, 0);
        __builtin_amdgcn_global_load_lds(GLB_AS(pa0 + rowskip + k0), LDS_AS(ldsA1), 16, 0, 0);
        __builtin_amdgcn_global_load_lds(GLB_AS(pb0 + k0),           LDS_AS(ldsB0), 16, 0, 0);
        __builtin_amdgcn_global_load_lds(GLB_AS(pb0 + rowskip + k0), LDS_AS(ldsB1), 16, 0, 0);
        __syncthreads();

        bf16x8 a[4], b[4];
#pragma unroll
        for (int i = 0; i < 4; i++)
            a[i] = *(const bf16x8*)&lA[(wm * 64 + i * 16 + l16) * 32 + quad * 8];
#pragma unroll
        for (int j = 0; j < 4; j++)
            b[j] = *(const bf16x8*)&lB[(wn * 64 + j * 16 + l16) * 32 + quad * 8];
#pragma unroll
        for (int i = 0; i < 4; i++)
#pragma unroll
            for (int j = 0; j < 4; j++)
                acc[i][j] = __builtin_amdgcn_mfma_f32_16x16x32_bf16(a[i], b[j], acc[i][j], 0, 0, 0);
        __syncthreads();
    }

    // C/D layout: row = quad*4 + r, col = l16
#pragma unroll
    for (int i = 0; i < 4; i++)
#pragma unroll
        for (int j = 0; j < 4; j++)
#pragma unroll
            for (int r = 0; r < 4; r++) {
                int row = bm + wm * 64 + i * 16 + quad * 4 + r;
                int col = bn + wn * 64 + j * 16 + l16;
                store_c(&C[(size_t)row * N + col], acc[i][j][r]);
            }
}

// ---------------------------------------------------------------------------
// RoPE in-place on bf16 X (4096 rows x ncols); cos/sin are FLOAT32 [2048][64].
// Each thread: 4 pairs (16 B of X).
// ---------------------------------------------------------------------------
__global__ __launch_bounds__(256) void rope_kernel(
    ushort* __restrict__ X, const float* __restrict__ cosv,
    const float* __restrict__ sinv, int ncols, int tprs)
{
    int gid = blockIdx.x * 256 + threadIdx.x;
    int m  = gid >> tprs;
    int pi = (gid & ((1 << tprs) - 1)) * 4;
    int t  = m & 2047;
    int i  = pi & 63;
    float4 c4 = *(const float4*)&cosv[t * 64 + i];
    float4 s4 = *(const float4*)&sinv[t * 64 + i];
    ushort* px = X + (size_t)m * ncols + pi * 2;
    uint4 d = *(const uint4*)px;
    unsigned int parts[4] = {d.x, d.y, d.z, d.w};
    float cc[4] = {c4.x, c4.y, c4.z, c4.w};
    float ss[4] = {s4.x, s4.y, s4.z, s4.w};
#pragma unroll
    for (int p = 0; p < 4; p++) {
        float re = bf2f((ushort)(parts[p] & 0xffffu));
        float im = bf2f((ushort)(parts[p] >> 16));
        float re2 = re * cc[p] - im * ss[p];
        float im2 = re * ss[p] + im * cc[p];
        parts[p] = (unsigned int)f2bf(re2) | ((unsigned int)f2bf(im2) << 16);
    }
    *(uint4*)px = make_uint4(parts[0], parts[1], parts[2], parts[3]);
}

// ---------------------------------------------------------------------------
// V transpose: V (4096 x 1024 bf16, row m=(b,t), col n=(kv,d)) -> Vt[b][n][t]
// ---------------------------------------------------------------------------
__global__ __launch_bounds__(256) void transpose_v(
    const ushort* __restrict__ V, ushort* __restrict__ Vt)
{
    __shared__ ushort tile[32][33];
    int n0 = blockIdx.x * 32, m0 = blockIdx.y * 32;
    int tx = threadIdx.x & 31, ty = threadIdx.x >> 5;
#pragma unroll
    for (int r = ty; r < 32; r += 8)
        tile[r][tx] = V[(size_t)(m0 + r) * 1024 + n0 + tx];
    __syncthreads();
    int b  = m0 >> 11;
    int t0 = m0 & 2047;
#pragma unroll
    for (int r = ty; r < 32; r += 8)
        Vt[(size_t)b * 2097152 + (size_t)(n0 + r) * 2048 + t0 + tx] = tile[tx][r];
}

// ---------------------------------------------------------------------------
// Flash attention (non-causal, 2048 keys). Grid (32 qtiles, 32 heads, 2 b),
// 256 threads = 4 waves x 16 query rows. Key tile = 32. All bf16.
// ---------------------------------------------------------------------------
__global__ __launch_bounds__(256) void flash_attn(
    const ushort* __restrict__ Q, const ushort* __restrict__ Kb,
    const ushort* __restrict__ Vt, ushort* __restrict__ ctx)
{
    __shared__ __align__(16) ushort lK[4 * 32 * 32];   // [ks][key][32]
    __shared__ __align__(16) ushort lV[128 * 32];      // [d][s]
    __shared__ __align__(16) ushort lP[4 * 16 * 32];   // per-wave P scratch

    const int qt = blockIdx.x, h = blockIdx.y, b = blockIdx.z;
    const int kv = h >> 2;
    const int tid = threadIdx.x, lane = tid & 63, w = tid >> 6;
    const int quad = lane >> 4, l16 = lane & 15;

    const int q0 = qt * 64 + w * 16;
    const size_t qrow = (size_t)(b * 2048 + q0 + l16) * 4096 + h * 128;
    bf16x8 aQ[4];
#pragma unroll
    for (int ks = 0; ks < 4; ks++)
        aQ[ks] = *(const bf16x8*)&Q[qrow + ks * 32 + quad * 8];

    f32x4 o[8];
#pragma unroll
    for (int d = 0; d < 8; d++) o[d] = (f32x4){0.f, 0.f, 0.f, 0.f};
    float mrow[4], lrow[4];
#pragma unroll
    for (int r = 0; r < 4; r++) { mrow[r] = -1e30f; lrow[r] = 0.f; }

    const ushort* gK = Kb + (size_t)(b * 2048) * 1024 + kv * 128;
    const ushort* gV = Vt + (size_t)(b * 8 + kv) * 128 * 2048;
    ushort* pw = &lP[w * 512];

    const int idx0 = tid, idx1 = 256 + tid;
    const int k_ks0 = idx0 >> 7, k_key0 = (idx0 >> 2) & 31, k_sub0 = idx0 & 3;
    const int k_ks1 = idx1 >> 7, k_key1 = (idx1 >> 2) & 31, k_sub1 = idx1 & 3;
    const int v_d0 = idx0 >> 2, v_sub0 = idx0 & 3;
    const int v_d1 = idx1 >> 2, v_sub1 = idx1 & 3;
    char* ldsK0 = (char*)lK + (tid & 192) * 16;
    char* ldsK1 = ldsK0 + 4096;
    char* ldsV0 = (char*)lV + (tid & 192) * 16;
    char* ldsV1 = ldsV0 + 4096;
    const float scale = 0.08838834764831845f;   // 1/sqrt(128)

    for (int s0 = 0; s0 < 2048; s0 += 32) {
        __builtin_amdgcn_global_load_lds(GLB_AS(gK + (size_t)(s0 + k_key0) * 1024 + k_ks0 * 32 + k_sub0 * 8),
                                         LDS_AS(ldsK0), 16, 0, 0);
        __builtin_amdgcn_global_load_lds(GLB_AS(gK + (size_t)(s0 + k_key1) * 1024 + k_ks1 * 32 + k_sub1 * 8),
                                         LDS_AS(ldsK1), 16, 0, 0);
        __builtin_amdgcn_global_load_lds(GLB_AS(gV + (size_t)v_d0 * 2048 + s0 + v_sub0 * 8),
                                         LDS_AS(ldsV0), 16, 0, 0);
        __builtin_amdgcn_global_load_lds(GLB_AS(gV + (size_t)v_d1 * 2048 + s0 + v_sub1 * 8),
                                         LDS_AS(ldsV1), 16, 0, 0);
        __syncthreads();

        f32x4 sc[2];
        sc[0] = (f32x4){0.f, 0.f, 0.f, 0.f};
        sc[1] = (f32x4){0.f, 0.f, 0.f, 0.f};
#pragma unroll
        for (int half = 0; half < 2; half++)
#pragma unroll
            for (int ks = 0; ks < 4; ks++) {
                bf16x8 bk = *(const bf16x8*)&lK[ks * 1024 + (half * 16 + l16) * 32 + quad * 8];
                sc[half] = __builtin_amdgcn_mfma_f32_16x16x32_bf16(aQ[ks], bk, sc[half], 0, 0, 0);
            }

        float p0[4], p1[4], alpha[4];
#pragma unroll
        for (int r = 0; r < 4; r++) {
            float s0v = sc[0][r] * scale;
            float s1v = sc[1][r] * scale;
            float mx = fmaxf(s0v, s1v);
#pragma unroll
            for (int off = 1; off < 16; off <<= 1)
                mx = fmaxf(mx, __shfl_xor(mx, off, 64));
            float mnew = fmaxf(mrow[r], mx);
            alpha[r] = __expf(mrow[r] - mnew);
            mrow[r] = mnew;
            p0[r] = __expf(s0v - mnew);
            p1[r] = __expf(s1v - mnew);
            float sum = p0[r] + p1[r];
#pragma unroll
            for (int off = 1; off < 16; off <<= 1)
                sum += __shfl_xor(sum, off, 64);
            lrow[r] = lrow[r] * alpha[r] + sum;
        }
#pragma unroll
        for (int d = 0; d < 8; d++)
#pragma unroll
            for (int r = 0; r < 4; r++) o[d][r] *= alpha[r];

#pragma unroll
        for (int r = 0; r < 4; r++) {
            pw[(quad * 4 + r) * 32 + l16]      = f2bf(p0[r]);
            pw[(quad * 4 + r) * 32 + 16 + l16] = f2bf(p1[r]);
        }
        bf16x8 aP = *(const bf16x8*)&pw[l16 * 32 + quad * 8];

#pragma unroll
        for (int d = 0; d < 8; d++) {
            bf16x8 bv = *(const bf16x8*)&lV[(d * 16 + l16) * 32 + quad * 8];
            o[d] = __builtin_amdgcn_mfma_f32_16x16x32_bf16(aP, bv, o[d], 0, 0, 0);
        }
        __syncthreads();
    }

    const int crow0 = b * 2048 + q0;
#pragma unroll
    for (int d = 0; d < 8; d++)
#pragma unroll
        for (int r = 0; r < 4; r++) {
            int row = crow0 + quad * 4 + r;
            ctx[(size_t)row * 4096 + h * 128 + d * 16 + l16] = f2bf(o[d][r] / lrow[r]);
        }
}

// ---------------------------------------------------------------------------
extern "C" void kernel_launch(void* const* d_in, const int* in_sizes, int n_in,
                              void* d_out, int out_size, void* d_ws, size_t ws_size,
                              hipStream_t stream)
{
    const float* x    = (const float*)d_in[0];
    const float* wq   = (const float*)d_in[1];
    const float* wk   = (const float*)d_in[2];
    const float* wv   = (const float*)d_in[3];
    const float* wo   = (const float*)d_in[4];
    const float* cosv = (const float*)d_in[7];
    const float* sinv = (const float*)d_in[8];
    float* out = (float*)d_out;

    // workspace (bf16 elements); ctx aliases Xb (dead after V gemm). 128 MB total.
    ushort* Xb   = (ushort*)d_ws;                  // 16M  (x bf16; later ctx)
    ushort* ctx  = Xb;
    ushort* Wbig = Xb   + (size_t)16 * 1024 * 1024; // 16M (wq, then wo)
    ushort* Wsm  = Wbig + (size_t)16 * 1024 * 1024; // 4M  (wk, then wv)
    ushort* Q    = Wsm  + (size_t)4  * 1024 * 1024; // 16M
    ushort* Kb   = Q    + (size_t)16 * 1024 * 1024; // 4M
    ushort* Vb   = Kb   + (size_t)4  * 1024 * 1024; // 4M
    ushort* Vt   = Vb   + (size_t)4  * 1024 * 1024; // 4M

    dim3 blk(256);
    cast_f2b<<<16384, blk, 0, stream>>>((const float4*)x,  (ushort4*)Xb,   4194304);
    cast_f2b<<<16384, blk, 0, stream>>>((const float4*)wq, (ushort4*)Wbig, 4194304);
    cast_f2b<<<4096,  blk, 0, stream>>>((const float4*)wk, (ushort4*)Wsm,  1048576);

    gemm_nt<<<dim3(32, 32), blk, 0, stream>>>(Xb, Wbig, Q,  4096, 4096, 4096);
    gemm_nt<<<dim3(8,  32), blk, 0, stream>>>(Xb, Wsm,  Kb, 4096, 1024, 4096);

    cast_f2b<<<4096,  blk, 0, stream>>>((const float4*)wv, (ushort4*)Wsm, 1048576);
    gemm_nt<<<dim3(8,  32), blk, 0, stream>>>(Xb, Wsm, Vb, 4096, 1024, 4096);

    cast_f2b<<<16384, blk, 0, stream>>>((const float4*)wo, (ushort4*)Wbig, 4194304);

    rope_kernel<<<8192, blk, 0, stream>>>(Q,  cosv, sinv, 4096, 9);
    rope_kernel<<<2048, blk, 0, stream>>>(Kb, cosv, sinv, 1024, 7);
    transpose_v<<<dim3(32, 128), blk, 0, stream>>>(Vb, Vt);
    flash_attn<<<dim3(32, 32, 2), blk, 0, stream>>>(Q, Kb, Vt, ctx);

    gemm_nt<<<dim3(32, 32), blk, 0, stream>>>(ctx, Wbig, out, 4096, 4096, 4096);
}

// Round 3
// 1186.366 us; speedup vs baseline: 1.0628x; 1.0628x over previous
//
#include <hip/hip_runtime.h>
#include <hip/hip_bf16.h>
#include <stdint.h>

// Attention_47528108097749: llama attention block. f32 in/out, bf16 MFMA inside.
// B=2, T=2048, D=4096, H=32, KV=8, HD=128. start_pos=0, mask unused (full attn).

typedef short bf16x8 __attribute__((ext_vector_type(8)));
typedef float f32x4  __attribute__((ext_vector_type(4)));

#define GLB_AS(p) ((__attribute__((address_space(1))) void*)(p))
#define LDS_AS(p) ((__attribute__((address_space(3))) void*)(p))

__device__ __forceinline__ float bf2f(ushort u) {
    union { unsigned int i; float f; } v; v.i = ((unsigned int)u) << 16; return v.f;
}
__device__ __forceinline__ ushort f2bf(float f) {
    union { float f; unsigned int i; } v; v.f = f;
    unsigned int r = v.i + 0x7FFFu + ((v.i >> 16) & 1u);   // RNE
    return (ushort)(r >> 16);
}
__device__ __forceinline__ unsigned int pk_bf16(float a, float b) {
    return (unsigned int)f2bf(a) | ((unsigned int)f2bf(b) << 16);
}
__device__ __forceinline__ void store_c(ushort* p, float v) { *p = f2bf(v); }
__device__ __forceinline__ void store_c(float*  p, float v) { *p = v; }

// ---------------------------------------------------------------------------
__global__ __launch_bounds__(256) void cast_f2b(
    const float4* __restrict__ src, ushort4* __restrict__ dst, int n4)
{
    int i = blockIdx.x * 256 + threadIdx.x;
    if (i < n4) {
        float4 v = src[i];
        ushort4 o;
        o.x = f2bf(v.x); o.y = f2bf(v.y); o.z = f2bf(v.z); o.w = f2bf(v.w);
        dst[i] = o;
    }
}

// ---------------------------------------------------------------------------
// NT GEMM (m97 structure): C[m][n] = sum_k A[m][k]*B[n][k], bf16 in, OT out.
// ---------------------------------------------------------------------------
template <typename OT>
__global__ __launch_bounds__(256) void gemm_nt(
    const ushort* __restrict__ A, const ushort* __restrict__ B,
    OT* __restrict__ C, int M, int N, int K)
{
    __shared__ __align__(16) ushort lA[128 * 32];
    __shared__ __align__(16) ushort lB[128 * 32];

    const int tid  = threadIdx.x;
    const int lane = tid & 63;
    const int w    = tid >> 6;
    const int wm   = w >> 1, wn = w & 1;
    const int quad = lane >> 4, l16 = lane & 15;
    const int bm   = blockIdx.y * 128, bn = blockIdx.x * 128;

    f32x4 acc[4][4];
#pragma unroll
    for (int i = 0; i < 4; i++)
#pragma unroll
        for (int j = 0; j < 4; j++) acc[i][j] = (f32x4){0.f, 0.f, 0.f, 0.f};

    const ushort* pa0 = A + (size_t)(bm + (tid >> 2)) * K + (tid & 3) * 8;
    const ushort* pb0 = B + (size_t)(bn + (tid >> 2)) * K + (tid & 3) * 8;
    char* ldsA0 = (char*)lA + (tid & 192) * 16;
    char* ldsA1 = ldsA0 + 4096;
    char* ldsB0 = (char*)lB + (tid & 192) * 16;
    char* ldsB1 = ldsB0 + 4096;
    const size_t rowskip = (size_t)64 * K;

    for (int k0 = 0; k0 < K; k0 += 32) {
        __builtin_amdgcn_global_load_lds(GLB_AS(pa0 + k0),           LDS_AS(ldsA0), 16, 0, 0);
        __builtin_amdgcn_global_load_lds(GLB_AS(pa0 + rowskip + k0), LDS_AS(ldsA1), 16, 0, 0);
        __builtin_amdgcn_global_load_lds(GLB_AS(pb0 + k0),           LDS_AS(ldsB0), 16, 0, 0);
        __builtin_amdgcn_global_load_lds(GLB_AS(pb0 + rowskip + k0), LDS_AS(ldsB1), 16, 0, 0);
        __syncthreads();

        bf16x8 a[4], b[4];
#pragma unroll
        for (int i = 0; i < 4; i++)
            a[i] = *(const bf16x8*)&lA[(wm * 64 + i * 16 + l16) * 32 + quad * 8];
#pragma unroll
        for (int j = 0; j < 4; j++)
            b[j] = *(const bf16x8*)&lB[(wn * 64 + j * 16 + l16) * 32 + quad * 8];
#pragma unroll
        for (int i = 0; i < 4; i++)
#pragma unroll
            for (int j = 0; j < 4; j++)
                acc[i][j] = __builtin_amdgcn_mfma_f32_16x16x32_bf16(a[i], b[j], acc[i][j], 0, 0, 0);
        __syncthreads();
    }

#pragma unroll
    for (int i = 0; i < 4; i++)
#pragma unroll
        for (int j = 0; j < 4; j++)
#pragma unroll
            for (int r = 0; r < 4; r++) {
                int row = bm + wm * 64 + i * 16 + quad * 4 + r;
                int col = bn + wn * 64 + j * 16 + l16;
                store_c(&C[(size_t)row * N + col], acc[i][j][r]);
            }
}

// ---------------------------------------------------------------------------
// RoPE in-place on bf16 X; row stride ldx, cos/sin f32 [2048][64].
// Optionally scales output (folds attention 1/sqrt(HD) into Q).
// ---------------------------------------------------------------------------
__global__ __launch_bounds__(256) void rope_kernel(
    ushort* __restrict__ X, const float* __restrict__ cosv,
    const float* __restrict__ sinv, int ldx, int tprs, float scale)
{
    int gid = blockIdx.x * 256 + threadIdx.x;
    int m  = gid >> tprs;
    int pi = (gid & ((1 << tprs) - 1)) * 4;
    int t  = m & 2047;
    int i  = pi & 63;
    float4 c4 = *(const float4*)&cosv[t * 64 + i];
    float4 s4 = *(const float4*)&sinv[t * 64 + i];
    ushort* px = X + (size_t)m * ldx + pi * 2;
    uint4 d = *(const uint4*)px;
    unsigned int parts[4] = {d.x, d.y, d.z, d.w};
    float cc[4] = {c4.x, c4.y, c4.z, c4.w};
    float ss[4] = {s4.x, s4.y, s4.z, s4.w};
#pragma unroll
    for (int p = 0; p < 4; p++) {
        float re = bf2f((ushort)(parts[p] & 0xffffu));
        float im = bf2f((ushort)(parts[p] >> 16));
        float re2 = (re * cc[p] - im * ss[p]) * scale;
        float im2 = (re * ss[p] + im * cc[p]) * scale;
        parts[p] = pk_bf16(re2, im2);
    }
    *(uint4*)px = make_uint4(parts[0], parts[1], parts[2], parts[3]);
}

// ---------------------------------------------------------------------------
// V transpose out of fused KV: KV rows (b,t) stride 2048, V = cols 1024..2047.
// Vt[b][n][t], n=(kv,d) in 0..1023.
// ---------------------------------------------------------------------------
__global__ __launch_bounds__(256) void transpose_v(
    const ushort* __restrict__ KV, ushort* __restrict__ Vt)
{
    __shared__ ushort tile[32][33];
    int n0 = blockIdx.x * 32, m0 = blockIdx.y * 32;
    int tx = threadIdx.x & 31, ty = threadIdx.x >> 5;
#pragma unroll
    for (int r = ty; r < 32; r += 8)
        tile[r][tx] = KV[(size_t)(m0 + r) * 2048 + 1024 + n0 + tx];
    __syncthreads();
    int b  = m0 >> 11;
    int t0 = m0 & 2047;
#pragma unroll
    for (int r = ty; r < 32; r += 8)
        Vt[(size_t)b * 2097152 + (size_t)(n0 + r) * 2048 + t0 + tx] = tile[tx][r];
}

// ---------------------------------------------------------------------------
// Flash attention, S^T scheme. Grid (32 qtiles, 32 h, 2 b), 4 waves x 16 q.
// Key tile = 64. Scores computed transposed: C row = key (in-register),
// col = q (lane) -> softmax state is one scalar/lane, reductions are 2 shfl.
// PV as O^T = V^T * P^T. Q pre-scaled by 1/sqrt(128) in rope.
// ---------------------------------------------------------------------------
__global__ __launch_bounds__(256) void flash_attn(
    const ushort* __restrict__ Q, const ushort* __restrict__ KV,
    const ushort* __restrict__ Vt, ushort* __restrict__ ctx)
{
    __shared__ __align__(16) ushort lK[64 * 128];    // [key][d]      16 KB
    __shared__ __align__(16) ushort lV[128 * 64];    // [d][s]        16 KB
    __shared__ __align__(16) ushort lP[4 * 16 * 72]; // per-wave [q][72] 9 KB

    const int qt = blockIdx.x, h = blockIdx.y, b = blockIdx.z;
    const int kv = h >> 2;
    const int tid = threadIdx.x, lane = tid & 63, w = tid >> 6;
    const int quad = lane >> 4, l16 = lane & 15;

    // Q as B-operand: B[n=q=l16][k=d=quad*8+j], per 32-d chunk
    const int q0 = qt * 64 + w * 16;
    const size_t qrow = (size_t)(b * 2048 + q0 + l16) * 4096 + h * 128;
    bf16x8 bQ[4];
#pragma unroll
    for (int ks = 0; ks < 4; ks++)
        bQ[ks] = *(const bf16x8*)&Q[qrow + ks * 32 + quad * 8];

    f32x4 o[8];
#pragma unroll
    for (int dc = 0; dc < 8; dc++) o[dc] = (f32x4){0.f, 0.f, 0.f, 0.f};
    float m = -1e30f, l = 0.f;

    const ushort* gK = KV + (size_t)(b * 2048) * 2048 + kv * 128;   // stride 2048
    const ushort* gV = Vt + (size_t)(b * 8 + kv) * 2048 * 128;      // [d][t]
    ushort* pw = &lP[w * 16 * 72];

    // staging: 1024 chunks of 16B each for K and V, 4 reps x 256 threads
    const int keyb = tid >> 4, dsub = tid & 15;   // K: key=rep*16+keyb, 16 chunks/row
    const int db   = tid >> 3, ssub = tid & 7;    // V: d=rep*32+db, 8 chunks/row
    char* ldsK = (char*)lK + (tid & 192) * 16;
    char* ldsV = (char*)lV + (tid & 192) * 16;

    for (int s0 = 0; s0 < 2048; s0 += 64) {
#pragma unroll
        for (int rep = 0; rep < 4; rep++) {
            __builtin_amdgcn_global_load_lds(
                GLB_AS(gK + (size_t)(s0 + rep * 16 + keyb) * 2048 + dsub * 8),
                LDS_AS(ldsK + rep * 4096), 16, 0, 0);
            __builtin_amdgcn_global_load_lds(
                GLB_AS(gV + (size_t)(rep * 32 + db) * 2048 + s0 + ssub * 8),
                LDS_AS(ldsV + rep * 4096), 16, 0, 0);
        }
        __syncthreads();

        // S^T[key][q]: A = K rows (16 keys/group), B = Q
        f32x4 scT[4];
#pragma unroll
        for (int g = 0; g < 4; g++) scT[g] = (f32x4){0.f, 0.f, 0.f, 0.f};
#pragma unroll
        for (int g = 0; g < 4; g++)
#pragma unroll
            for (int ks = 0; ks < 4; ks++) {
                bf16x8 aK = *(const bf16x8*)&lK[(g * 16 + l16) * 128 + ks * 32 + quad * 8];
                scT[g] = __builtin_amdgcn_mfma_f32_16x16x32_bf16(aK, bQ[ks], scT[g], 0, 0, 0);
            }

        // online softmax: lane holds 16 keys (quad*4+r + g*16) for q=l16
        float tmax = scT[0][0];
#pragma unroll
        for (int g = 0; g < 4; g++)
#pragma unroll
            for (int r = 0; r < 4; r++) tmax = fmaxf(tmax, scT[g][r]);
        tmax = fmaxf(tmax, __shfl_xor(tmax, 16, 64));
        tmax = fmaxf(tmax, __shfl_xor(tmax, 32, 64));
        float mnew = fmaxf(m, tmax);
        if (__any(mnew > m)) {
            float alpha = __expf(m - mnew);
            m = mnew;
            l *= alpha;
#pragma unroll
            for (int dc = 0; dc < 8; dc++)
#pragma unroll
                for (int r = 0; r < 4; r++) o[dc][r] *= alpha;
        }
        float p[16];
        float ts = 0.f;
#pragma unroll
        for (int i = 0; i < 16; i++) {
            p[i] = __expf(scT[i >> 2][i & 3] - m);
            ts += p[i];
        }
        ts += __shfl_xor(ts, 16, 64);
        ts += __shfl_xor(ts, 32, 64);
        l += ts;

        // P^T -> LDS [q][s] (s = g*16 + quad*4 + r), b64 writes, stride 72
#pragma unroll
        for (int g = 0; g < 4; g++) {
            uint2 pk;
            pk.x = pk_bf16(p[g * 4 + 0], p[g * 4 + 1]);
            pk.y = pk_bf16(p[g * 4 + 2], p[g * 4 + 3]);
            *(uint2*)&pw[l16 * 72 + g * 16 + quad * 4] = pk;
        }
        bf16x8 bP[2];
#pragma unroll
        for (int c = 0; c < 2; c++)
            bP[c] = *(const bf16x8*)&pw[l16 * 72 + c * 32 + quad * 8];

        // O^T += V^T * P^T
#pragma unroll
        for (int dc = 0; dc < 8; dc++)
#pragma unroll
            for (int c = 0; c < 2; c++) {
                bf16x8 aV = *(const bf16x8*)&lV[(dc * 16 + l16) * 64 + c * 32 + quad * 8];
                o[dc] = __builtin_amdgcn_mfma_f32_16x16x32_bf16(aV, bP[c], o[dc], 0, 0, 0);
            }
        __syncthreads();
    }

    // epilogue: lane has O^T[d = dc*16+quad*4+r][q = l16]; row = q
    float inv = 1.0f / l;
#pragma unroll
    for (int dc = 0; dc < 8; dc++) {
        uint2 pk;
        pk.x = pk_bf16(o[dc][0] * inv, o[dc][1] * inv);
        pk.y = pk_bf16(o[dc][2] * inv, o[dc][3] * inv);
        *(uint2*)&ctx[qrow + dc * 16 + quad * 4] = pk;
    }
}

// ---------------------------------------------------------------------------
extern "C" void kernel_launch(void* const* d_in, const int* in_sizes, int n_in,
                              void* d_out, int out_size, void* d_ws, size_t ws_size,
                              hipStream_t stream)
{
    const float* x    = (const float*)d_in[0];
    const float* wq   = (const float*)d_in[1];
    const float* wk   = (const float*)d_in[2];
    const float* wv   = (const float*)d_in[3];
    const float* wo   = (const float*)d_in[4];
    const float* cosv = (const float*)d_in[7];
    const float* sinv = (const float*)d_in[8];
    float* out = (float*)d_out;

    // workspace (ushort units), 64M ushort = 128 MB total via aliasing
    ushort* Xb   = (ushort*)d_ws;                    // 16M: x bf16; later ctx
    ushort* ctx  = Xb;
    ushort* Wbig = Xb   + (size_t)16 * 1024 * 1024;  // 16M: wq, then wo
    ushort* Wsm  = Wbig + (size_t)16 * 1024 * 1024;  //  8M: [wk;wv]; later Vt
    ushort* Vt   = Wsm;
    ushort* Q    = Wsm  + (size_t)8  * 1024 * 1024;  // 16M
    ushort* KV   = Q    + (size_t)16 * 1024 * 1024;  //  8M: [K|V] cols, stride 2048

    dim3 blk(256);
    cast_f2b<<<16384, blk, 0, stream>>>((const float4*)x,  (ushort4*)Xb,   4194304);
    cast_f2b<<<16384, blk, 0, stream>>>((const float4*)wq, (ushort4*)Wbig, 4194304);
    cast_f2b<<<4096,  blk, 0, stream>>>((const float4*)wk, (ushort4*)Wsm,  1048576);
    cast_f2b<<<4096,  blk, 0, stream>>>((const float4*)wv, (ushort4*)(Wsm + (size_t)4194304), 1048576);

    gemm_nt<<<dim3(32, 32), blk, 0, stream>>>(Xb, Wbig, Q,  4096, 4096, 4096);
    gemm_nt<<<dim3(16, 32), blk, 0, stream>>>(Xb, Wsm,  KV, 4096, 2048, 4096);

    cast_f2b<<<16384, blk, 0, stream>>>((const float4*)wo, (ushort4*)Wbig, 4194304);

    rope_kernel<<<8192, blk, 0, stream>>>(Q,  cosv, sinv, 4096, 9, 0.08838834764831845f);
    rope_kernel<<<2048, blk, 0, stream>>>(KV, cosv, sinv, 2048, 7, 1.0f);
    transpose_v<<<dim3(32, 128), blk, 0, stream>>>(KV, Vt);

    flash_attn<<<dim3(32, 32, 2), blk, 0, stream>>>(Q, KV, Vt, ctx);

    gemm_nt<<<dim3(32, 32), blk, 0, stream>>>(ctx, Wbig, out, 4096, 4096, 4096);
}

// Round 4
// 1016.906 us; speedup vs baseline: 1.2399x; 1.1666x over previous
//
#include <hip/hip_runtime.h>
#include <hip/hip_bf16.h>
#include <stdint.h>

// Attention_47528108097749: llama attention block. f32 in/out, bf16 MFMA inside.
// B=2, T=2048, D=4096, H=32, KV=8, HD=128. start_pos=0, mask unused (full attn).

typedef short bf16x8 __attribute__((ext_vector_type(8)));
typedef float f32x4  __attribute__((ext_vector_type(4)));

#define GLB_AS(p) ((__attribute__((address_space(1))) void*)(p))
#define LDS_AS(p) ((__attribute__((address_space(3))) void*)(p))

__device__ __forceinline__ float bf2f(ushort u) {
    union { unsigned int i; float f; } v; v.i = ((unsigned int)u) << 16; return v.f;
}
__device__ __forceinline__ ushort f2bf(float f) {
    union { float f; unsigned int i; } v; v.f = f;
    unsigned int r = v.i + 0x7FFFu + ((v.i >> 16) & 1u);   // RNE
    return (ushort)(r >> 16);
}
__device__ __forceinline__ unsigned int pk_bf16(float a, float b) {
    return (unsigned int)f2bf(a) | ((unsigned int)f2bf(b) << 16);
}
__device__ __forceinline__ void store_c(ushort* p, float v) { *p = f2bf(v); }
__device__ __forceinline__ void store_c(float*  p, float v) { *p = v; }

// ---------------------------------------------------------------------------
__global__ __launch_bounds__(256) void cast_f2b(
    const float4* __restrict__ src, ushort4* __restrict__ dst, int n4)
{
    int i = blockIdx.x * 256 + threadIdx.x;
    if (i < n4) {
        float4 v = src[i];
        ushort4 o;
        o.x = f2bf(v.x); o.y = f2bf(v.y); o.z = f2bf(v.z); o.w = f2bf(v.w);
        dst[i] = o;
    }
}

// ---------------------------------------------------------------------------
// NT GEMM (m97 structure): C[m][n] = sum_k A[m][k]*B[n][k], bf16 in, OT out.
// ---------------------------------------------------------------------------
template <typename OT>
__global__ __launch_bounds__(256) void gemm_nt(
    const ushort* __restrict__ A, const ushort* __restrict__ B,
    OT* __restrict__ C, int M, int N, int K)
{
    __shared__ __align__(16) ushort lA[128 * 32];
    __shared__ __align__(16) ushort lB[128 * 32];

    const int tid  = threadIdx.x;
    const int lane = tid & 63;
    const int w    = tid >> 6;
    const int wm   = w >> 1, wn = w & 1;
    const int quad = lane >> 4, l16 = lane & 15;
    const int bm   = blockIdx.y * 128, bn = blockIdx.x * 128;

    f32x4 acc[4][4];
#pragma unroll
    for (int i = 0; i < 4; i++)
#pragma unroll
        for (int j = 0; j < 4; j++) acc[i][j] = (f32x4){0.f, 0.f, 0.f, 0.f};

    const ushort* pa0 = A + (size_t)(bm + (tid >> 2)) * K + (tid & 3) * 8;
    const ushort* pb0 = B + (size_t)(bn + (tid >> 2)) * K + (tid & 3) * 8;
    char* ldsA0 = (char*)lA + (tid & 192) * 16;
    char* ldsA1 = ldsA0 + 4096;
    char* ldsB0 = (char*)lB + (tid & 192) * 16;
    char* ldsB1 = ldsB0 + 4096;
    const size_t rowskip = (size_t)64 * K;

    for (int k0 = 0; k0 < K; k0 += 32) {
        __builtin_amdgcn_global_load_lds(GLB_AS(pa0 + k0),           LDS_AS(ldsA0), 16, 0, 0);
        __builtin_amdgcn_global_load_lds(GLB_AS(pa0 + rowskip + k0), LDS_AS(ldsA1), 16, 0, 0);
        __builtin_amdgcn_global_load_lds(GLB_AS(pb0 + k0),           LDS_AS(ldsB0), 16, 0, 0);
        __builtin_amdgcn_global_load_lds(GLB_AS(pb0 + rowskip + k0), LDS_AS(ldsB1), 16, 0, 0);
        __syncthreads();

        bf16x8 a[4], b[4];
#pragma unroll
        for (int i = 0; i < 4; i++)
            a[i] = *(const bf16x8*)&lA[(wm * 64 + i * 16 + l16) * 32 + quad * 8];
#pragma unroll
        for (int j = 0; j < 4; j++)
            b[j] = *(const bf16x8*)&lB[(wn * 64 + j * 16 + l16) * 32 + quad * 8];
#pragma unroll
        for (int i = 0; i < 4; i++)
#pragma unroll
            for (int j = 0; j < 4; j++)
                acc[i][j] = __builtin_amdgcn_mfma_f32_16x16x32_bf16(a[i], b[j], acc[i][j], 0, 0, 0);
        __syncthreads();
    }

#pragma unroll
    for (int i = 0; i < 4; i++)
#pragma unroll
        for (int j = 0; j < 4; j++)
#pragma unroll
            for (int r = 0; r < 4; r++) {
                int row = bm + wm * 64 + i * 16 + quad * 4 + r;
                int col = bn + wn * 64 + j * 16 + l16;
                store_c(&C[(size_t)row * N + col], acc[i][j][r]);
            }
}

// ---------------------------------------------------------------------------
// RoPE in-place on bf16 X; row stride ldx, cos/sin f32 [2048][64].
// Scale folds attention 1/sqrt(HD) into Q.
// ---------------------------------------------------------------------------
__global__ __launch_bounds__(256) void rope_kernel(
    ushort* __restrict__ X, const float* __restrict__ cosv,
    const float* __restrict__ sinv, int ldx, int tprs, float scale)
{
    int gid = blockIdx.x * 256 + threadIdx.x;
    int m  = gid >> tprs;
    int pi = (gid & ((1 << tprs) - 1)) * 4;
    int t  = m & 2047;
    int i  = pi & 63;
    float4 c4 = *(const float4*)&cosv[t * 64 + i];
    float4 s4 = *(const float4*)&sinv[t * 64 + i];
    ushort* px = X + (size_t)m * ldx + pi * 2;
    uint4 d = *(const uint4*)px;
    unsigned int parts[4] = {d.x, d.y, d.z, d.w};
    float cc[4] = {c4.x, c4.y, c4.z, c4.w};
    float ss[4] = {s4.x, s4.y, s4.z, s4.w};
#pragma unroll
    for (int p = 0; p < 4; p++) {
        float re = bf2f((ushort)(parts[p] & 0xffffu));
        float im = bf2f((ushort)(parts[p] >> 16));
        float re2 = (re * cc[p] - im * ss[p]) * scale;
        float im2 = (re * ss[p] + im * cc[p]) * scale;
        parts[p] = pk_bf16(re2, im2);
    }
    *(uint4*)px = make_uint4(parts[0], parts[1], parts[2], parts[3]);
}

// ---------------------------------------------------------------------------
// V transpose out of fused KV: KV rows (b,t) stride 2048, V = cols 1024..2047.
// Vt[b][n][t], n=(kv,d) in 0..1023.
// ---------------------------------------------------------------------------
__global__ __launch_bounds__(256) void transpose_v(
    const ushort* __restrict__ KV, ushort* __restrict__ Vt)
{
    __shared__ ushort tile[32][33];
    int n0 = blockIdx.x * 32, m0 = blockIdx.y * 32;
    int tx = threadIdx.x & 31, ty = threadIdx.x >> 5;
#pragma unroll
    for (int r = ty; r < 32; r += 8)
        tile[r][tx] = KV[(size_t)(m0 + r) * 2048 + 1024 + n0 + tx];
    __syncthreads();
    int b  = m0 >> 11;
    int t0 = m0 & 2047;
#pragma unroll
    for (int r = ty; r < 32; r += 8)
        Vt[(size_t)b * 2097152 + (size_t)(n0 + r) * 2048 + t0 + tx] = tile[tx][r];
}

// ---------------------------------------------------------------------------
// Flash attention, S^T scheme, XOR-swizzled LDS tiles (conflict-free b128).
// Grid (32 qtiles, 32 h, 2 b), 4 waves x 16 q. Key tile = 64.
// lK stored as [key][chunk ^ (key&15)] (16-B chunks); lV as [d][chunk ^ (d&7)].
// Swizzle is applied by permuting global_load_lds SOURCE addresses (dest must
// stay lane-contiguous), and un-applied in the ds_read addressing.
// ---------------------------------------------------------------------------
__global__ __launch_bounds__(256) void flash_attn(
    const ushort* __restrict__ Q, const ushort* __restrict__ KV,
    const ushort* __restrict__ Vt, ushort* __restrict__ ctx)
{
    __shared__ __align__(16) ushort lK[64 * 128];    // [key][d-swizzled] 16 KB
    __shared__ __align__(16) ushort lV[128 * 64];    // [d][s-swizzled]   16 KB
    __shared__ __align__(16) ushort lP[4 * 16 * 72]; // per-wave [q][72]   9 KB

    const int qt = blockIdx.x, h = blockIdx.y, b = blockIdx.z;
    const int kv = h >> 2;
    const int tid = threadIdx.x, lane = tid & 63, w = tid >> 6;
    const int quad = lane >> 4, l16 = lane & 15;

    const int q0 = qt * 64 + w * 16;
    const size_t qrow = (size_t)(b * 2048 + q0 + l16) * 4096 + h * 128;
    bf16x8 bQ[4];
#pragma unroll
    for (int ks = 0; ks < 4; ks++)
        bQ[ks] = *(const bf16x8*)&Q[qrow + ks * 32 + quad * 8];

    f32x4 o[8];
#pragma unroll
    for (int dc = 0; dc < 8; dc++) o[dc] = (f32x4){0.f, 0.f, 0.f, 0.f};
    float m = -1e30f, l = 0.f;

    const ushort* gK = KV + (size_t)(b * 2048) * 2048 + kv * 128;   // stride 2048
    const ushort* gV = Vt + (size_t)(b * 8 + kv) * 2048 * 128;      // [d][t]
    ushort* pw = &lP[w * 16 * 72];

    // staging decomposition (swizzled source chunks):
    //  K: slot = rep*256+tid = key*16+dslot; key = rep*16+(tid>>4), dslot = tid&15
    //     global d-chunk = dslot ^ (key & 15) = dsub ^ keyb
    //  V: slot = d*8+sslot; d = rep*32+(tid>>3), sslot = tid&7
    //     global s-chunk = sslot ^ (d & 7) = ssub ^ (db & 7)
    const int keyb = tid >> 4, dsub = tid & 15;
    const int db   = tid >> 3, ssub = tid & 7;
    const int kswz = (dsub ^ keyb) * 8;            // ushort offset within K row
    const int vswz = (ssub ^ (db & 7)) * 8;        // ushort offset within V row
    char* ldsK = (char*)lK + (tid & 192) * 16;
    char* ldsV = (char*)lV + (tid & 192) * 16;

    for (int s0 = 0; s0 < 2048; s0 += 64) {
#pragma unroll
        for (int rep = 0; rep < 4; rep++) {
            __builtin_amdgcn_global_load_lds(
                GLB_AS(gK + (size_t)(s0 + rep * 16 + keyb) * 2048 + kswz),
                LDS_AS(ldsK + rep * 4096), 16, 0, 0);
            __builtin_amdgcn_global_load_lds(
                GLB_AS(gV + (size_t)(rep * 32 + db) * 2048 + s0 + vswz),
                LDS_AS(ldsV + rep * 4096), 16, 0, 0);
        }
        __syncthreads();

        // S^T[key][q]: A = K rows (16 keys/group), B = Q
        f32x4 scT[4];
#pragma unroll
        for (int g = 0; g < 4; g++) scT[g] = (f32x4){0.f, 0.f, 0.f, 0.f};
#pragma unroll
        for (int g = 0; g < 4; g++)
#pragma unroll
            for (int ks = 0; ks < 4; ks++) {
                // key = g*16+l16; chunk ks*4+quad, swizzled by key&15 = l16
                bf16x8 aK = *(const bf16x8*)&lK[(g * 16 + l16) * 128 + ((ks * 4 + quad) ^ l16) * 8];
                scT[g] = __builtin_amdgcn_mfma_f32_16x16x32_bf16(aK, bQ[ks], scT[g], 0, 0, 0);
            }

        // online softmax: lane holds 16 keys for q = l16
        float tmax = scT[0][0];
#pragma unroll
        for (int g = 0; g < 4; g++)
#pragma unroll
            for (int r = 0; r < 4; r++) tmax = fmaxf(tmax, scT[g][r]);
        tmax = fmaxf(tmax, __shfl_xor(tmax, 16, 64));
        tmax = fmaxf(tmax, __shfl_xor(tmax, 32, 64));
        float mnew = fmaxf(m, tmax);
        if (__any(mnew > m)) {
            float alpha = __expf(m - mnew);
            m = mnew;
            l *= alpha;
#pragma unroll
            for (int dc = 0; dc < 8; dc++)
#pragma unroll
                for (int r = 0; r < 4; r++) o[dc][r] *= alpha;
        }
        float p[16];
        float ts = 0.f;
#pragma unroll
        for (int i = 0; i < 16; i++) {
            p[i] = __expf(scT[i >> 2][i & 3] - m);
            ts += p[i];
        }
        ts += __shfl_xor(ts, 16, 64);
        ts += __shfl_xor(ts, 32, 64);
        l += ts;

        // P^T -> LDS [q][s] (s = g*16 + quad*4 + r), b64 writes, stride 72
#pragma unroll
        for (int g = 0; g < 4; g++) {
            uint2 pk;
            pk.x = pk_bf16(p[g * 4 + 0], p[g * 4 + 1]);
            pk.y = pk_bf16(p[g * 4 + 2], p[g * 4 + 3]);
            *(uint2*)&pw[l16 * 72 + g * 16 + quad * 4] = pk;
        }
        bf16x8 bP[2];
#pragma unroll
        for (int c = 0; c < 2; c++)
            bP[c] = *(const bf16x8*)&pw[l16 * 72 + c * 32 + quad * 8];

        // O^T += V^T * P^T
#pragma unroll
        for (int dc = 0; dc < 8; dc++)
#pragma unroll
            for (int c = 0; c < 2; c++) {
                // d = dc*16+l16; chunk c*4+quad, swizzled by d&7 = l16&7
                bf16x8 aV = *(const bf16x8*)&lV[(dc * 16 + l16) * 64 + ((c * 4 + quad) ^ (l16 & 7)) * 8];
                o[dc] = __builtin_amdgcn_mfma_f32_16x16x32_bf16(aV, bP[c], o[dc], 0, 0, 0);
            }
        __syncthreads();
    }

    // epilogue: lane has O^T[d = dc*16+quad*4+r][q = l16]
    float inv = 1.0f / l;
#pragma unroll
    for (int dc = 0; dc < 8; dc++) {
        uint2 pk;
        pk.x = pk_bf16(o[dc][0] * inv, o[dc][1] * inv);
        pk.y = pk_bf16(o[dc][2] * inv, o[dc][3] * inv);
        *(uint2*)&ctx[qrow + dc * 16 + quad * 4] = pk;
    }
}

// ---------------------------------------------------------------------------
extern "C" void kernel_launch(void* const* d_in, const int* in_sizes, int n_in,
                              void* d_out, int out_size, void* d_ws, size_t ws_size,
                              hipStream_t stream)
{
    const float* x    = (const float*)d_in[0];
    const float* wq   = (const float*)d_in[1];
    const float* wk   = (const float*)d_in[2];
    const float* wv   = (const float*)d_in[3];
    const float* wo   = (const float*)d_in[4];
    const float* cosv = (const float*)d_in[7];
    const float* sinv = (const float*)d_in[8];
    float* out = (float*)d_out;

    // workspace (ushort units), 128 MB total via aliasing
    ushort* Xb   = (ushort*)d_ws;                    // 16M: x bf16; later ctx
    ushort* ctx  = Xb;
    ushort* Wbig = Xb   + (size_t)16 * 1024 * 1024;  // 16M: wq, then wo
    ushort* Wsm  = Wbig + (size_t)16 * 1024 * 1024;  //  8M: [wk;wv]; later Vt
    ushort* Vt   = Wsm;
    ushort* Q    = Wsm  + (size_t)8  * 1024 * 1024;  // 16M
    ushort* KV   = Q    + (size_t)16 * 1024 * 1024;  //  8M: [K|V] cols, stride 2048

    dim3 blk(256);
    cast_f2b<<<16384, blk, 0, stream>>>((const float4*)x,  (ushort4*)Xb,   4194304);
    cast_f2b<<<16384, blk, 0, stream>>>((const float4*)wq, (ushort4*)Wbig, 4194304);
    cast_f2b<<<4096,  blk, 0, stream>>>((const float4*)wk, (ushort4*)Wsm,  1048576);
    cast_f2b<<<4096,  blk, 0, stream>>>((const float4*)wv, (ushort4*)(Wsm + (size_t)4194304), 1048576);

    gemm_nt<<<dim3(32, 32), blk, 0, stream>>>(Xb, Wbig, Q,  4096, 4096, 4096);
    gemm_nt<<<dim3(16, 32), blk, 0, stream>>>(Xb, Wsm,  KV, 4096, 2048, 4096);

    cast_f2b<<<16384, blk, 0, stream>>>((const float4*)wo, (ushort4*)Wbig, 4194304);

    rope_kernel<<<8192, blk, 0, stream>>>(Q,  cosv, sinv, 4096, 9, 0.08838834764831845f);
    rope_kernel<<<2048, blk, 0, stream>>>(KV, cosv, sinv, 2048, 7, 1.0f);
    transpose_v<<<dim3(32, 128), blk, 0, stream>>>(KV, Vt);

    flash_attn<<<dim3(32, 32, 2), blk, 0, stream>>>(Q, KV, Vt, ctx);

    gemm_nt<<<dim3(32, 32), blk, 0, stream>>>(ctx, Wbig, out, 4096, 4096, 4096);
}